// Round 17
// baseline (46.813 us; speedup 1.0000x reference)
//
#include <hip/hip_runtime.h>

typedef _Float16 f16;
typedef __fp16 h2 __attribute__((ext_vector_type(2)));
typedef f16 f16x4 __attribute__((ext_vector_type(4)));
typedef f16 f16x8 __attribute__((ext_vector_type(8)));
typedef float f32x4 __attribute__((ext_vector_type(4)));
typedef float f32x16 __attribute__((ext_vector_type(16)));
typedef unsigned int uint32;

#define FIN  64
#define FOUT 64
#define HI   128
#define WI   128
#define HO   126
#define WO   126
#define HIWI (HI*WI)
#define NPH  8       // phases; each stages 8 channels (4 per wave-group)
#define TR   8       // tile rows
#define TC   16      // tile cols
#define SR   10      // staged rows (TR+2)
#define ROWDW 36     // dwords per staged row: 17 slots x 2dw + 2 pad (16B mult)
#define CHSTR (SR*ROWDW)     // 360 dwords per channel slot
#define ONES_DW (8*CHSTR)    // 2880: ones window (bias slot), 2 dwords
#define XBUF (ONES_DW+2)     // 2882 dwords per buffer

// ws: B-fragment table f16 [i][ob][lane][8] = 128 KiB; Wc f16-pair table
// u32 [ipair][o] = 8 KiB at u32 offset 32768.
// k-labeling (validated rounds 6-16): k = g*4+(j&3)+8*(j>>2), g=lane>>5;
// taps k=4*dy+dx (dx<3 real, dx=3 zero-weight), k12 = bias (pixel side 1.0h).
// LDS layout (this round): pre-assembled window slots — slot s at row R holds
// f16x4 of input cols (col0+s .. col0+s+3); 4-slot groups XOR-swizzled by row
// (cg ^= R&3) for bank spread. Hot loop = 2x ds_read_b64 per channel, no
// extraction VALU.
// LESSONS: (r11) no address-of MFMA results; (r12) no register arrays by
// reference; (r14) watch VGPR budget — spills show as GB-scale FETCH/WRITE.

__global__ __launch_bounds__(256) void prepass(
    const float* __restrict__ Wf, const float* __restrict__ bf,
    const float* __restrict__ Wc, unsigned short* __restrict__ ws)
{
    int t = blockIdx.x * 256 + threadIdx.x;   // 0..10239
    if (t < 8192) {
        int i  = t >> 7;
        int ob = (t >> 6) & 1;
        int l  = t & 63;
        int g  = l >> 5, n = l & 31;
        int o  = ob * 32 + n;
        unsigned short h[8];
#pragma unroll
        for (int j = 0; j < 8; ++j) {
            int k = g * 4 + (j & 3) + 8 * (j >> 2);
            float v = 0.0f;
            if (k < 12) {
                int dy = k >> 2, dx = k & 3;
                if (dx < 3) v = Wf[((size_t)o * FIN + i) * 9 + dy * 3 + dx];
            } else if (k == 12) {
                v = bf[o * FIN + i];
            }
            f16 hv = (f16)v;
            h[j] = *(unsigned short*)&hv;
        }
        uint4 pk;
        pk.x = h[0] | ((uint32)h[1] << 16);
        pk.y = h[2] | ((uint32)h[3] << 16);
        pk.z = h[4] | ((uint32)h[5] << 16);
        pk.w = h[6] | ((uint32)h[7] << 16);
        *(uint4*)&ws[(size_t)t * 8] = pk;
    } else if (t < 8192 + 2048) {
        int t2 = t - 8192;
        int ip = t2 >> 6, o = t2 & 63;
        f16 lo = (f16)Wc[(size_t)o * FIN + 2 * ip];
        f16 hi = (f16)Wc[(size_t)o * FIN + 2 * ip + 1];
        uint32 v = (uint32)*(unsigned short*)&lo |
                   ((uint32)*(unsigned short*)&hi << 16);
        ((uint32*)ws)[32768 + t2] = v;
    }
}

__global__ __launch_bounds__(512, 4) void conv_mfma(
    const float* __restrict__ x,  const float* __restrict__ bc,
    const unsigned short* __restrict__ ws, float* __restrict__ out)
{
    __shared__ __align__(16) union {
        struct { uint32 xsl[2][XBUF]; uint32 wcp[32][34]; } a;  // 27.4 KB
        float part[4][64][16];                                  // 16.4 KB
        float ot[32][132];                                      // 16.9 KB
    } sm;

    const int tid = threadIdx.x;          // 0..511, 8 waves
    const int l   = tid & 63, w = tid >> 6;
    const int wg  = w >> 2;               // channel group: 0 -> i 0..31, 1 -> 32..63
    const int wl  = w & 3;                // wave-in-group
    const int g   = l >> 5;
    const int m   = l & 31;               // pixel row idx on loads; o on output
    const int prow = m >> 2;
    const int wg4 = wg * 4;
    const int ibase = wg * 32;

    // XCD-group swizzle: all 16 blocks sharing (rx,b) -> same fid%8 (same XCD)
    const int fid    = blockIdx.x;
    const int grp    = (fid >> 7) * 8 + (fid & 7);   // 0..63 = rx + 16*b
    const int member = (fid >> 3) & 15;              // cy + 8*oh
    const int rx = grp & 15, b = grp >> 4;
    const int cy = member & 7, oh = member >> 3;
    const int row0 = rx * TR;
    const int col0 = cy * TC;
    const int o_lane = oh * 32 + m;

    // ---- stage Wc pair table [oo][ip] (1024 u32, once) ----
    {
        const uint32* wsrc = ((const uint32*)ws) + 32768;
#pragma unroll
        for (int k = 0; k < 2; ++k) {
            int idx = tid + k * 512;                  // 0..1023
            int oo = idx >> 5, ip = idx & 31;
            sm.a.wcp[oo][ip] = wsrc[(size_t)ip * 64 + oh * 32 + oo];
        }
    }
    // ones windows (bias slot source), both buffers
    if (tid < 4) {
        int bufi = tid >> 1, d = tid & 1;
        sm.a.xsl[bufi][ONES_DW + d] = d ? 0u : 0x00003c00u;
    }

    // ---- staging map: wave w stages channel slot w; 40 lanes build windows ----
    const float* xb = x + (size_t)b * FIN * HIWI;
    const bool stg = (l < 40);
    int goffA = 0, goffB = 0, widx = 0;
    if (stg) {
        int r = l >> 2, cg = l & 3;
        int cgsw = cg ^ (r & 3);               // row-group XOR swizzle
        int gy = min(row0 + r, HI - 1);        // clamps feed discarded outputs only
        int c0 = col0 + 4 * cg;
        goffA = gy * WI + min(c0, WI - 4);
        goffB = gy * WI + min(c0 + 4, WI - 4);
        widx = w * CHSTR + r * ROWDW + cgsw * 8;
    }
    const int chbase = wg * 32 + wl;           // slot w's channel at phase 0

    // prologue: stage phase 0 (channels {0..3, 32..35}) into buffer 0
    if (stg) {
        f32x4 vA = *(const f32x4*)&xb[(size_t)chbase * HIWI + goffA];
        f32x4 vB = *(const f32x4*)&xb[(size_t)chbase * HIWI + goffB];
        uint32 u0 = __builtin_bit_cast(uint32, __builtin_amdgcn_cvt_pkrtz(vA[0], vA[1]));
        uint32 u1 = __builtin_bit_cast(uint32, __builtin_amdgcn_cvt_pkrtz(vA[1], vA[2]));
        uint32 u2 = __builtin_bit_cast(uint32, __builtin_amdgcn_cvt_pkrtz(vA[2], vA[3]));
        uint32 u3 = __builtin_bit_cast(uint32, __builtin_amdgcn_cvt_pkrtz(vA[3], vB[0]));
        uint32 u4 = __builtin_bit_cast(uint32, __builtin_amdgcn_cvt_pkrtz(vB[0], vB[1]));
        uint32 u5 = __builtin_bit_cast(uint32, __builtin_amdgcn_cvt_pkrtz(vB[1], vB[2]));
        uint32* dst = &sm.a.xsl[0][widx];
        *(uint4*)(dst + 0) = (uint4){u0, u2, u1, u3};   // slots cg0,cg1
        *(uint4*)(dst + 4) = (uint4){u2, u4, u3, u5};   // slots cg2,cg3
    }

    // B-fragment prefetch for phase 0 (this group's channels)
    const uint4* Btab = (const uint4*)ws;
    uint4 Bc[4], Bn[4];
#pragma unroll
    for (int c4 = 0; c4 < 4; ++c4)
        Bc[c4] = Btab[(size_t)((ibase + c4) * 2 + oh) * 64 + l];

    f32x16 acc = {}, zero = {};
    const h2 zh = {(__fp16)0.0f, (__fp16)0.0f};

    // hoisted read offsets (per-thread constants, swizzled slots)
    const int R1  = prow + g;
    const int r1off = R1 * ROWDW + (4 * (wl ^ (R1 & 3)) + (m & 3)) * 2;
    const int R2  = prow + 2;
    const int r2off = g ? ONES_DW : (R2 * ROWDW + (4 * (wl ^ (R2 & 3)) + (m & 3)) * 2);
    const int r2str = g ? 0 : CHSTR;

    for (int ph = 0; ph < NPH; ++ph) {         // plain loop: arrays stay in VGPRs
        const int cur = ph & 1;
        const bool more = (ph + 1 < NPH);

        f32x4 svA = {}, svB = {};
        if (more) {
            const size_t chn = (size_t)(chbase + (ph + 1) * 4) * HIWI;
            if (stg) {
                svA = *(const f32x4*)&xb[chn + goffA];
                svB = *(const f32x4*)&xb[chn + goffB];
            }
#pragma unroll
            for (int c4 = 0; c4 < 4; ++c4)
                Bn[c4] = Btab[(size_t)((ibase + (ph + 1) * 4 + c4) * 2 + oh) * 64 + l];
        }

        __syncthreads();   // buf[cur] writes from previous phase visible

        const uint32 wcu0 = sm.a.wcp[m][wg * 16 + ph * 2];
        const uint32 wcu1 = sm.a.wcp[m][wg * 16 + ph * 2 + 1];
        const uint32* base = sm.a.xsl[cur];

#pragma unroll
        for (int c2 = 0; c2 < 2; ++c2) {       // channel pairs
            const int ch0 = 2 * c2, ch1 = 2 * c2 + 1;
            uint2 A1a = *(const uint2*)(base + (wg4 + ch0) * CHSTR + r1off);
            uint2 A2a = *(const uint2*)(base + (wg4 + ch0) * r2str + r2off);
            uint4 auv0 = {A1a.x, A1a.y, A2a.x, A2a.y};
            f16x8 Af0 = *(f16x8*)&auv0;
            f32x16 S0 = __builtin_amdgcn_mfma_f32_32x32x16_f16(
                            Af0, *(f16x8*)&Bc[ch0], zero, 0, 0, 0);

            uint2 A1b = *(const uint2*)(base + (wg4 + ch1) * CHSTR + r1off);
            uint2 A2b = *(const uint2*)(base + (wg4 + ch1) * r2str + r2off);
            uint4 auv1 = {A1b.x, A1b.y, A2b.x, A2b.y};
            f16x8 Af1 = *(f16x8*)&auv1;
            f32x16 S1 = __builtin_amdgcn_mfma_f32_32x32x16_f16(
                            Af1, *(f16x8*)&Bc[ch1], zero, 0, 0, 0);

            const uint32 wcu = c2 ? wcu1 : wcu0;
            h2 wch;
            {
                uint32 t = wcu;
                wch = *(h2*)&t;            // local scalar, SSA-safe (r16-proven)
            }
#pragma unroll
            for (int r = 0; r < 16; ++r) {
                h2 p = __builtin_amdgcn_cvt_pkrtz(S0[r], S1[r]);
                p = __builtin_elementwise_max(p, zh);              // v_pk_max_f16
                acc[r] = __builtin_amdgcn_fdot2(p, wch, acc[r], false);
            }
        }

        if (more) {
            if (stg) {
                uint32 u0 = __builtin_bit_cast(uint32, __builtin_amdgcn_cvt_pkrtz(svA[0], svA[1]));
                uint32 u1 = __builtin_bit_cast(uint32, __builtin_amdgcn_cvt_pkrtz(svA[1], svA[2]));
                uint32 u2 = __builtin_bit_cast(uint32, __builtin_amdgcn_cvt_pkrtz(svA[2], svA[3]));
                uint32 u3 = __builtin_bit_cast(uint32, __builtin_amdgcn_cvt_pkrtz(svA[3], svB[0]));
                uint32 u4 = __builtin_bit_cast(uint32, __builtin_amdgcn_cvt_pkrtz(svB[0], svB[1]));
                uint32 u5 = __builtin_bit_cast(uint32, __builtin_amdgcn_cvt_pkrtz(svB[1], svB[2]));
                uint32* dst = &sm.a.xsl[cur ^ 1][widx];
                *(uint4*)(dst + 0) = (uint4){u0, u2, u1, u3};
                *(uint4*)(dst + 4) = (uint4){u2, u4, u3, u5};
            }
#pragma unroll
            for (int c4 = 0; c4 < 4; ++c4) Bc[c4] = Bn[c4];
        }
    }

    // ---- combine the two channel groups via LDS (deterministic fp32) ----
    __syncthreads();                       // all xsl reads done (part aliases xsl)
    if (wg == 1) {
#pragma unroll
        for (int r = 0; r < 16; ++r) sm.part[wl][l][r] = acc[r];
    }
    __syncthreads();
    if (wg == 0) {
#pragma unroll
        for (int r = 0; r < 16; ++r) acc[r] += sm.part[wl][l][r];
    }
    __syncthreads();                       // part reads done (ot aliases part)

    // ---- transpose: ot[o][px] (group-0 waves only) ----
    if (wg == 0) {
        const float bcv = bc[o_lane];
#pragma unroll
        for (int r = 0; r < 16; ++r) {
            int p  = (r & 3) + 8 * (r >> 2) + 4 * g;             // wave-local pixel
            int px = (p >> 2) * TC + wl * 4 + (p & 3);
            sm.ot[m][px] = acc[r] + bcv;
        }
    }
    __syncthreads();

    // ---- stores: one 16-col row chunk (64B) per thread (first 256 threads) ----
    if (tid < 256) {
        const int oo  = tid >> 3;          // 0..31
        const int seg = tid & 7;           // tile row
        const int o   = oh * 32 + oo;
        const int ho  = row0 + seg;
        if (ho < HO) {
            const float* src = &sm.ot[oo][seg * TC];
            size_t base = ((size_t)(b * FOUT + o) * HO + ho) * WO + col0;
            if (col0 + TC <= WO) {
#pragma unroll
                for (int c = 0; c < TC; ++c) out[base + c] = src[c];
            } else {
#pragma unroll
                for (int c = 0; c < 14; ++c) out[base + c] = src[c];
            }
        }
    }
}

extern "C" void kernel_launch(void* const* d_in, const int* in_sizes, int n_in,
                              void* d_out, int out_size, void* d_ws, size_t ws_size,
                              hipStream_t stream) {
    const float* x  = (const float*)d_in[0];
    const float* Wf = (const float*)d_in[1];
    const float* bf = (const float*)d_in[2];
    const float* Wc = (const float*)d_in[3];
    const float* bc = (const float*)d_in[4];
    float* out = (float*)d_out;
    unsigned short* ws = (unsigned short*)d_ws;

    hipLaunchKernelGGL(prepass, dim3(40), dim3(256), 0, stream, Wf, bf, Wc, ws);

    // 1024 blocks x 512 threads: 16 rx x (8 cy x 2 oh) x 4 b, XCD-group swizzled
    hipLaunchKernelGGL(conv_mfma, dim3(1024), dim3(512), 0, stream,
                       x, bc, ws, out);
}

// Round 18
// 40.481 us; speedup vs baseline: 1.1564x; 1.1564x over previous
//
#include <hip/hip_runtime.h>

typedef _Float16 f16;
typedef __fp16 h2 __attribute__((ext_vector_type(2)));
typedef f16 f16x8 __attribute__((ext_vector_type(8)));
typedef float f32x16 __attribute__((ext_vector_type(16)));
typedef unsigned int uint32;

#define FIN  64
#define FOUT 64
#define HI   128
#define WI   128
#define HO   126
#define WO   126
#define HIWI (HI*WI)
#define TR   8       // tile rows
#define TC   16      // tile cols

// ws: B-fragment table f16 [i][ob][lane][8] = 128 KiB; Wc f16-pair table
// u32 [ipair][o] = 8 KiB at u32 offset 32768.
// k-labeling (validated rounds 6-17): k = g*4+(j&3)+8*(j>>2), g=lane>>5;
// taps k=4*dy+dx (dx<3 real, dx=3 zero-weight -> 4th window value is
// don't-care), k12 = bias (pixel side supplies 1.0h; k13..15 = 0).
// LESSONS: (r11) no address-of MFMA results; (r12) no register arrays by
// reference; (r14) watch VGPR budget — spills show as GB-scale FETCH/WRITE.
// This round: NO LDS staging, NO hot-loop barriers — per-lane direct global
// window loads (L2-hot via XCD swizzle), depth-1 by-value prefetch.

__global__ __launch_bounds__(256) void prepass(
    const float* __restrict__ Wf, const float* __restrict__ bf,
    const float* __restrict__ Wc, unsigned short* __restrict__ ws)
{
    int t = blockIdx.x * 256 + threadIdx.x;   // 0..10239
    if (t < 8192) {
        int i  = t >> 7;
        int ob = (t >> 6) & 1;
        int l  = t & 63;
        int g  = l >> 5, n = l & 31;
        int o  = ob * 32 + n;
        unsigned short h[8];
#pragma unroll
        for (int j = 0; j < 8; ++j) {
            int k = g * 4 + (j & 3) + 8 * (j >> 2);
            float v = 0.0f;
            if (k < 12) {
                int dy = k >> 2, dx = k & 3;
                if (dx < 3) v = Wf[((size_t)o * FIN + i) * 9 + dy * 3 + dx];
            } else if (k == 12) {
                v = bf[o * FIN + i];
            }
            f16 hv = (f16)v;
            h[j] = *(unsigned short*)&hv;
        }
        uint4 pk;
        pk.x = h[0] | ((uint32)h[1] << 16);
        pk.y = h[2] | ((uint32)h[3] << 16);
        pk.z = h[4] | ((uint32)h[5] << 16);
        pk.w = h[6] | ((uint32)h[7] << 16);
        *(uint4*)&ws[(size_t)t * 8] = pk;
    } else if (t < 8192 + 2048) {
        int t2 = t - 8192;
        int ip = t2 >> 6, o = t2 & 63;
        f16 lo = (f16)Wc[(size_t)o * FIN + 2 * ip];
        f16 hi = (f16)Wc[(size_t)o * FIN + 2 * ip + 1];
        uint32 v = (uint32)*(unsigned short*)&lo |
                   ((uint32)*(unsigned short*)&hi << 16);
        ((uint32*)ws)[32768 + t2] = v;
    }
}

// per-pair prefetch registers (all by-value, SROA-safe)
struct PR {
    float a10, a11, a12, a20, a21, a22;   // channel a: row1 3 cols, row2 3 cols
    float b10, b11, b12, b20, b21, b22;   // channel b
    uint4 aB, bB;                         // B-fragments
    uint32 wcu;                           // packed f16 Wc pair
};

__device__ __forceinline__ PR loadPair(const float* xb, const uint4* Btab,
                                       const uint32* wct, int ip,
                                       int goff1, int goff2, int oh, int l,
                                       int o_lane)
{
    PR r;
    const float* xa = xb + (size_t)(2 * ip) * HIWI;
    const float* xc = xa + HIWI;
    r.a10 = xa[goff1]; r.a11 = xa[goff1 + 1]; r.a12 = xa[goff1 + 2];
    r.a20 = xa[goff2]; r.a21 = xa[goff2 + 1]; r.a22 = xa[goff2 + 2];
    r.b10 = xc[goff1]; r.b11 = xc[goff1 + 1]; r.b12 = xc[goff1 + 2];
    r.b20 = xc[goff2]; r.b21 = xc[goff2 + 1]; r.b22 = xc[goff2 + 2];
    r.aB = Btab[(size_t)((2 * ip) * 2 + oh) * 64 + l];
    r.bB = Btab[(size_t)((2 * ip + 1) * 2 + oh) * 64 + l];
    r.wcu = wct[ip * 64 + o_lane];
    return r;
}

__global__ __launch_bounds__(256, 4) void conv_mfma(
    const float* __restrict__ x,  const float* __restrict__ bc,
    const unsigned short* __restrict__ ws, float* __restrict__ out)
{
    __shared__ float ot[32][132];         // output transpose buffer only

    const int tid = threadIdx.x;          // 0..255, 4 waves
    const int l   = tid & 63, w = tid >> 6;
    const int g   = l >> 5;
    const int m   = l & 31;               // pixel idx on A; o on C/D
    const int prow = m >> 2;

    // XCD-group swizzle: all 16 blocks sharing (rx,b) -> same fid%8 (same XCD)
    const int fid    = blockIdx.x;
    const int grp    = (fid >> 7) * 8 + (fid & 7);   // 0..63 = rx + 16*b
    const int member = (fid >> 3) & 15;              // cy + 8*oh
    const int rx = grp & 15, b = grp >> 4;
    const int cy = member & 7, oh = member >> 3;
    const int row0 = rx * TR;
    const int col0 = cy * TC;
    const int o_lane = oh * 32 + m;

    // hoisted per-lane window offsets (clamped lanes feed discarded outputs)
    const int gy1 = min(row0 + prow + g, HI - 1);
    const int gy2 = min(row0 + prow + 2, HI - 1);
    const int cc  = min(col0 + w * 4 + (m & 3), WI - 3);  // cols cc..cc+2 valid
    const int goff1 = gy1 * WI + cc;
    const int goff2 = gy2 * WI + cc;

    const float*  xb   = x + (size_t)b * FIN * HIWI;
    const uint4*  Btab = (const uint4*)ws;
    const uint32* wct  = ((const uint32*)ws) + 32768;

    f32x16 acc = {};
    const f32x16 zero = {};
    const h2 zh = {(__fp16)0.0f, (__fp16)0.0f};

    PR cur = loadPair(xb, Btab, wct, 0, goff1, goff2, oh, l, o_lane);

#pragma unroll 4
    for (int ip = 0; ip < 31; ++ip) {
        PR nxt = loadPair(xb, Btab, wct, ip + 1, goff1, goff2, oh, l, o_lane);

        // ---- compute current pair ----
        {
            uint32 a0 = __builtin_bit_cast(uint32, __builtin_amdgcn_cvt_pkrtz(cur.a10, cur.a11));
            uint32 a1 = __builtin_bit_cast(uint32, __builtin_amdgcn_cvt_pkrtz(cur.a12, cur.a12));
            uint32 a2 = g ? 0x00003c00u
                          : __builtin_bit_cast(uint32, __builtin_amdgcn_cvt_pkrtz(cur.a20, cur.a21));
            uint32 a3 = g ? 0u
                          : __builtin_bit_cast(uint32, __builtin_amdgcn_cvt_pkrtz(cur.a22, cur.a22));
            uint4 av = {a0, a1, a2, a3};
            f32x16 S0 = __builtin_amdgcn_mfma_f32_32x32x16_f16(
                __builtin_bit_cast(f16x8, av), __builtin_bit_cast(f16x8, cur.aB),
                zero, 0, 0, 0);

            uint32 b0 = __builtin_bit_cast(uint32, __builtin_amdgcn_cvt_pkrtz(cur.b10, cur.b11));
            uint32 b1 = __builtin_bit_cast(uint32, __builtin_amdgcn_cvt_pkrtz(cur.b12, cur.b12));
            uint32 b2 = g ? 0x00003c00u
                          : __builtin_bit_cast(uint32, __builtin_amdgcn_cvt_pkrtz(cur.b20, cur.b21));
            uint32 b3 = g ? 0u
                          : __builtin_bit_cast(uint32, __builtin_amdgcn_cvt_pkrtz(cur.b22, cur.b22));
            uint4 bv = {b0, b1, b2, b3};
            f32x16 S1 = __builtin_amdgcn_mfma_f32_32x32x16_f16(
                __builtin_bit_cast(f16x8, bv), __builtin_bit_cast(f16x8, cur.bB),
                zero, 0, 0, 0);

            h2 wch = __builtin_bit_cast(h2, cur.wcu);
#pragma unroll
            for (int r = 0; r < 16; ++r) {
                h2 q = __builtin_amdgcn_cvt_pkrtz(S0[r], S1[r]);
                q = __builtin_elementwise_max(q, zh);
                acc[r] = __builtin_amdgcn_fdot2(q, wch, acc[r], false);
            }
        }
        cur = nxt;
    }
    // ---- last pair (ip = 31) ----
    {
        uint32 a0 = __builtin_bit_cast(uint32, __builtin_amdgcn_cvt_pkrtz(cur.a10, cur.a11));
        uint32 a1 = __builtin_bit_cast(uint32, __builtin_amdgcn_cvt_pkrtz(cur.a12, cur.a12));
        uint32 a2 = g ? 0x00003c00u
                      : __builtin_bit_cast(uint32, __builtin_amdgcn_cvt_pkrtz(cur.a20, cur.a21));
        uint32 a3 = g ? 0u
                      : __builtin_bit_cast(uint32, __builtin_amdgcn_cvt_pkrtz(cur.a22, cur.a22));
        uint4 av = {a0, a1, a2, a3};
        f32x16 S0 = __builtin_amdgcn_mfma_f32_32x32x16_f16(
            __builtin_bit_cast(f16x8, av), __builtin_bit_cast(f16x8, cur.aB),
            zero, 0, 0, 0);

        uint32 b0 = __builtin_bit_cast(uint32, __builtin_amdgcn_cvt_pkrtz(cur.b10, cur.b11));
        uint32 b1 = __builtin_bit_cast(uint32, __builtin_amdgcn_cvt_pkrtz(cur.b12, cur.b12));
        uint32 b2 = g ? 0x00003c00u
                      : __builtin_bit_cast(uint32, __builtin_amdgcn_cvt_pkrtz(cur.b20, cur.b21));
        uint32 b3 = g ? 0u
                      : __builtin_bit_cast(uint32, __builtin_amdgcn_cvt_pkrtz(cur.b22, cur.b22));
        uint4 bv = {b0, b1, b2, b3};
        f32x16 S1 = __builtin_amdgcn_mfma_f32_32x32x16_f16(
            __builtin_bit_cast(f16x8, bv), __builtin_bit_cast(f16x8, cur.bB),
            zero, 0, 0, 0);

        h2 wch = __builtin_bit_cast(h2, cur.wcu);
#pragma unroll
        for (int r = 0; r < 16; ++r) {
            h2 q = __builtin_amdgcn_cvt_pkrtz(S0[r], S1[r]);
            q = __builtin_elementwise_max(q, zh);
            acc[r] = __builtin_amdgcn_fdot2(q, wch, acc[r], false);
        }
    }

    // ---- transpose: ot[o][px] then coalesced stores ----
    const float bcv = bc[o_lane];
#pragma unroll
    for (int r = 0; r < 16; ++r) {
        int p  = (r & 3) + 8 * (r >> 2) + 4 * g;             // wave-local pixel
        int px = (p >> 2) * TC + w * 4 + (p & 3);
        ot[m][px] = acc[r] + bcv;
    }
    __syncthreads();

    {
        const int oo  = tid >> 3;          // 0..31
        const int seg = tid & 7;           // tile row
        const int o   = oh * 32 + oo;
        const int ho  = row0 + seg;
        if (ho < HO) {
            const float* src = &ot[oo][seg * TC];
            size_t base = ((size_t)(b * FOUT + o) * HO + ho) * WO + col0;
            if (col0 + TC <= WO) {
#pragma unroll
                for (int c = 0; c < TC; ++c) out[base + c] = src[c];
            } else {
#pragma unroll
                for (int c = 0; c < 14; ++c) out[base + c] = src[c];
            }
        }
    }
}

extern "C" void kernel_launch(void* const* d_in, const int* in_sizes, int n_in,
                              void* d_out, int out_size, void* d_ws, size_t ws_size,
                              hipStream_t stream) {
    const float* x  = (const float*)d_in[0];
    const float* Wf = (const float*)d_in[1];
    const float* bf = (const float*)d_in[2];
    const float* Wc = (const float*)d_in[3];
    const float* bc = (const float*)d_in[4];
    float* out = (float*)d_out;
    unsigned short* ws = (unsigned short*)d_ws;

    hipLaunchKernelGGL(prepass, dim3(40), dim3(256), 0, stream, Wf, bf, Wc, ws);

    // 1024 blocks x 256 threads: 16 rx x (8 cy x 2 oh) x 4 b, XCD-group swizzled
    hipLaunchKernelGGL(conv_mfma, dim3(1024), dim3(256), 0, stream,
                       x, bc, ws, out);
}